// Round 19
// baseline (1873.095 us; speedup 1.0000x reference)
//
#include <hip/hip_runtime.h>
#include <stdint.h>

#define T_STEPS 256
#define EMBD 10
#define MB 16          // batch rows per block
#define NBLK 64        // 1024 / MB
#define NKIT 9         // K = 288 = 9 * 32 (256 h + 10 x + 1 bias + pad)

typedef __attribute__((ext_vector_type(8))) short bf16x8;
typedef __attribute__((ext_vector_type(4))) float f32x4;
typedef __attribute__((ext_vector_type(4))) int   i32x4;

__device__ __forceinline__ unsigned short f2bf(float f) {
    union { float f; unsigned int u; } v; v.f = f;
    unsigned int u = v.u;
    unsigned int r = (u + 0x7FFFu + ((u >> 16) & 1u)) >> 16;  // RNE
    return (unsigned short)r;
}
__device__ __forceinline__ float sig_fast(float x) {
    return __frcp_rn(1.0f + exp2f(-1.4426950408889634f * x));
}
__device__ __forceinline__ float tanh_fast(float x) {
    return 1.0f - 2.0f * __frcp_rn(exp2f(2.8853900817779268f * x) + 1.0f);
}

// Direct global -> AGPR load with EMBEDDED wait (R14-proven: passed on HW).
// Contiguous AGPR quad; builtin MFMA consumes it directly as the B operand
// (gfx950 unified RF) -- zero per-use VALU, and the allocator cannot
// restream or spill AGPR storage. The embedded s_waitcnt makes the quad
// architecturally valid at asm exit (separate-fence variants NaN'd:
// allocator copies could be scheduled before the fence -- R9/R10/R13).
__device__ __forceinline__ i32x4 load_b_agpr(const i32x4* p) {
    i32x4 r;
    asm volatile("global_load_dwordx4 %0, %1, off\n\t"
                 "s_waitcnt vmcnt(0)"
                 : "=a"(r) : "v"(p) : "memory");
    return r;
}
__device__ __forceinline__ f32x4 mfma_v(i32x4 a, i32x4 b, f32x4 c) {
    return __builtin_amdgcn_mfma_f32_16x16x32_bf16(
        __builtin_bit_cast(bf16x8, a), __builtin_bit_cast(bf16x8, b), c, 0, 0, 0);
}

// ---------------------------------------------------------------------------
// K1: swizzled bf16 weights Wfull[288][1024] in MFMA B-frag order.
// Main region: [kit 0..8][ntile 0..63][lane] x 16B.
// Stream region (kits 4,7,8): [w][s][gate][u][lane] -- wave-major constant
// offsets (K2 uses s=0 (kit4), s=1 (kit7)).
// ---------------------------------------------------------------------------
__global__ __launch_bounds__(64) void build_wswz(
    const float* __restrict__ Wgx, const float* __restrict__ Wgh, const float* __restrict__ bg,
    const float* __restrict__ Wix, const float* __restrict__ Wih, const float* __restrict__ bi,
    const float* __restrict__ Wfx, const float* __restrict__ Wfh, const float* __restrict__ bf_,
    const float* __restrict__ Wox, const float* __restrict__ Woh, const float* __restrict__ bo,
    unsigned short* __restrict__ wswz, unsigned short* __restrict__ sbuf)
{
    int g   = blockIdx.x / NKIT;   // ntile
    int kit = blockIdx.x % NKIT;
    int lane = threadIdx.x;
    int n = g * 16 + (lane & 15);
    int q = n >> 8;
    int col = n & 255;
    const float* Wh = (q == 0) ? Wgh : (q == 1) ? Wih : (q == 2) ? Wfh : Woh;
    const float* Wx = (q == 0) ? Wgx : (q == 1) ? Wix : (q == 2) ? Wfx : Wox;
    const float* bb = (q == 0) ? bg  : (q == 1) ? bi  : (q == 2) ? bf_ : bo;
    int k0 = kit * 32 + (lane >> 4) * 8;

    int4 out;
    unsigned short* p = (unsigned short*)&out;
#pragma unroll
    for (int jx = 0; jx < 8; jx++) {
        int k = k0 + jx;
        float v = 0.0f;
        if (k < 256)             v = Wh[k * 256 + col];
        else if (k < 256 + EMBD) v = Wx[(k - 256) * 256 + col];
        else if (k == 266)       v = bb[col];
        p[jx] = f2bf(v);
    }
    ((int4*)wswz)[(kit * 64 + g) * 64 + lane] = out;

    if (kit == 4 || kit == 7 || kit == 8) {
        int s    = (kit == 4) ? 0 : (kit == 7) ? 1 : 2;
        int gate = g >> 4;
        int wv   = (g & 15) >> 1;
        int u    = g & 1;
        ((int4*)sbuf)[((((wv * 3 + s) * 4 + gate) * 2 + u) * 64) + lane] = out;
    }
}

// ---------------------------------------------------------------------------
// K2: persistent LSTM. 64 blocks x 512 threads (8 waves, 2 waves/SIMD;
// unified RF = 256/wave: 128 arch + 128 AGPR).
// Wave w owns hcols 32w+16u+l15 (u=0,1) x 4 gates: nt = gate*16 + 2w + u.
// B residency/wave: kits {0,1,2,3} in contiguous AGPR quads (128 AGPR,
// consumed DIRECTLY by builtin MFMA -- no unpark VALU; R14 proved this
// path's correctness), kits {5,6} LDS (128 KB), kit {8} arch (32 regs),
// kits {4,7} streamed (128 KB/step/CU) via a 4-frag rotating land buffer.
// A-frags for kits 0-3 hoisted once per step (u-invariant) -- halves the
// redundant ds_read_b128 traffic. Arch demand ~112 < 128 (K-loop
// spill-free per R18's one-time-only WRITE_SIZE).
// ---------------------------------------------------------------------------
__global__ __launch_bounds__(512)
__attribute__((amdgpu_waves_per_eu(2, 2)))
void lstm_main(
    const int*   __restrict__ xtok,   // [1024][1][256]
    const float* __restrict__ emb,    // [32000][10]
    const float* __restrict__ Wph,    // [256][10]
    const float* __restrict__ bp,     // [10]
    const unsigned short* __restrict__ wswz,
    const unsigned short* __restrict__ sbuf,
    float* __restrict__ out)          // [1024][10]
{
    __shared__ __align__(16) unsigned short A_lds[2][8 * 64 * 8];   // 16 KB (kits 0-7)
    __shared__ __align__(16) unsigned short A8_lds[2][64 * 8];      // 2 KB (kit 8)
    __shared__ __align__(16) i32x4 B_lds[2 * 64 * 64];              // 128 KB (kits 5,6)
    __shared__ float outacc[MB * 10];

    const int tid  = threadIdx.x;
    const int w    = tid >> 6;        // wave 0..7
    const int lane = tid & 63;
    const int quad = lane >> 4;
    const int l15  = lane & 15;
    const int blk  = blockIdx.x;

    const int m_x = tid >> 4;         // x-gather: batch row 0..15 (tid<256)
    const int e_x = tid & 15;         // emb element (valid if <10)

    const i32x4* Bg  = (const i32x4*)wswz;
    const i32x4* SBw = (const i32x4*)sbuf + (size_t)w * (3 * 4 * 2 * 64);

    // --- prologue: LDS B-cache (kits 5,6) ---
    for (int i = tid; i < 2 * 64 * 64; i += 512)
        B_lds[i] = Bg[5 * 4096 + i];

    // --- AGPR-resident B: kits 0..3, [kit][gate][u] = 32 frags = 128 AGPR ---
    i32x4 bag[4][4][2];
#pragma unroll
    for (int s = 0; s < 4; s++)
#pragma unroll
        for (int g = 0; g < 4; g++)
#pragma unroll
            for (int u = 0; u < 2; u++)
                bag[s][g][u] = load_b_agpr(
                    &Bg[(s * 64 + g * 16 + 2 * w + u) * 64 + lane]);

    // --- arch-resident kit 8: [gate][u] = 8 frags = 32 regs ---
    i32x4 b8[4][2];
#pragma unroll
    for (int g = 0; g < 4; g++)
#pragma unroll
        for (int u = 0; u < 2; u++)
            b8[g][u] = Bg[(8 * 64 + g * 16 + 2 * w + u) * 64 + lane];

    // --- rotating land buffer: holds kit4(u=0) on loop entry ---
    i32x4 land[4];
#pragma unroll
    for (int g = 0; g < 4; g++)
        land[g] = SBw[(((0 * 4 + g) * 2 + 0) * 64) + lane];

    // --- init A double buffer: zeros, bias row (both), x_0 (buf 0) ---
    {
        int4 z4 = {0, 0, 0, 0};
        for (int i = tid; i < 1024; i += 512) ((int4*)A_lds)[i] = z4;
        if (tid < 128) ((int4*)A8_lds)[tid] = z4;
    }
    __syncthreads();
    if (tid < 16) {
        // kit8 local k=10 (bias=1.0): lp = m+16, elem 2
        A8_lds[0][(16 + tid) * 8 + 2] = 0x3F80;
        A8_lds[1][(16 + tid) * 8 + 2] = 0x3F80;
    }
    if (tid < 256 && e_x < EMBD) {
        int tok = xtok[(blk * MB + m_x) * T_STEPS + 0];
        float v = emb[tok * EMBD + e_x];
        A8_lds[0][(m_x + 16 * (e_x >> 3)) * 8 + (e_x & 7)] = f2bf(v);
    }
    __syncthreads();

    float c[2][4];
#pragma unroll
    for (int u = 0; u < 2; u++)
#pragma unroll
        for (int r = 0; r < 4; r++) c[u][r] = 0.0f;

    for (int t = 0; t < T_STEPS; t++) {
        const i32x4* Ab  = (const i32x4*)A_lds[t & 1];
        const i32x4* A8b = (const i32x4*)A8_lds[t & 1];
        unsigned short* Aw  = A_lds[(t + 1) & 1];
        unsigned short* A8w = A8_lds[(t + 1) & 1];

        // x(t+1) prefetch (independent; overlaps MFMA)
        float xval = 0.0f;
        const bool do_x = (t < T_STEPS - 1) && (tid < 256) && (e_x < EMBD);
        if ((t < T_STEPS - 1) && (tid < 256)) {
            int tok = xtok[(blk * MB + m_x) * T_STEPS + (t + 1)];
            if (e_x < EMBD) xval = emb[tok * EMBD + e_x];
        }

        // hoist u-invariant A-frags for kits 0..3 (read once per step)
        i32x4 aA03[4];
#pragma unroll
        for (int s = 0; s < 4; s++) aA03[s] = Ab[s * 64 + lane];

#pragma unroll
        for (int u = 0; u < 2; u++) {
            const int nu = 1 - u;  // next-pass index (t-invariant addresses)

            f32x4 acc[4];
#pragma unroll
            for (int g = 0; g < 4; g++) acc[g] = (f32x4){0.f, 0.f, 0.f, 0.f};

            // --- kit 4 (streamed; load landed last pass) ---
            {
                i32x4 a4 = Ab[4 * 64 + lane];
#pragma unroll
                for (int g = 0; g < 4; g++) acc[g] = mfma_v(a4, land[g], acc[g]);
            }
            // rotate: issue kit 7(u) into land (consumed ~20 MFMAs later)
#pragma unroll
            for (int g = 0; g < 4; g++)
                land[g] = SBw[(((1 * 4 + g) * 2 + u) * 64) + lane];

            // --- kit 8 (arch-resident) ---
            {
                i32x4 a8 = A8b[lane];
#pragma unroll
                for (int g = 0; g < 4; g++)
                    acc[g] = mfma_v(a8, b8[g][u], acc[g]);
            }
            // --- AGPR kits 0..3: B read straight from AGPR quads ---
#pragma unroll
            for (int s = 0; s < 4; s++) {
#pragma unroll
                for (int g = 0; g < 4; g++)
                    acc[g] = mfma_v(aA03[s], bag[s][g][u], acc[g]);
            }
            // --- LDS kit 5 ---
            {
                i32x4 a5 = Ab[5 * 64 + lane];
#pragma unroll
                for (int g = 0; g < 4; g++)
                    acc[g] = mfma_v(a5, B_lds[(g * 16 + 2 * w + u) * 64 + lane], acc[g]);
            }
            // --- kit 7 (streamed; issued this pass, ~20 MFMAs cover) ---
            {
                i32x4 a7 = Ab[7 * 64 + lane];
#pragma unroll
                for (int g = 0; g < 4; g++) acc[g] = mfma_v(a7, land[g], acc[g]);
            }
            // rotate: issue next pass's kit 4 (cross-pass/barrier cover)
#pragma unroll
            for (int g = 0; g < 4; g++)
                land[g] = SBw[(((0 * 4 + g) * 2 + nu) * 64) + lane];

            // --- LDS kit 6 ---
            {
                i32x4 a6 = Ab[6 * 64 + lane];
#pragma unroll
                for (int g = 0; g < 4; g++)
                    acc[g] = mfma_v(a6, B_lds[4096 + (g * 16 + 2 * w + u) * 64 + lane], acc[g]);
            }

            // gate math: z[m][n], m = quad*4+r, n = gate*256 + 32w + 16u + l15
            const int hcol = 32 * w + 16 * u + l15;
            const int lpbase = 16 * ((hcol >> 3) & 3);
#pragma unroll
            for (int r = 0; r < 4; r++) {
                float gg = tanh_fast(acc[0][r]);
                float ii = sig_fast(acc[1][r]);
                float ff = sig_fast(acc[2][r]);
                float oo = sig_fast(acc[3][r]);
                float cn = gg * ii + c[u][r] * ff;
                c[u][r] = cn;
                float hh = tanh_fast(cn) * oo;
                int m = quad * 4 + r;
                Aw[(w * 64 + m + lpbase) * 8 + (hcol & 7)] = f2bf(hh);
            }
        }
        if (t == T_STEPS - 1) break;
        if (do_x)
            A8w[(m_x + 16 * (e_x >> 3)) * 8 + (e_x & 7)] = f2bf(xval);
        __syncthreads();  // single barrier: A(t+1) complete
    }
    __syncthreads();

    // --- epilogue: re-read own h (bf16) from final A buffer, project ---
    const unsigned short* Af = A_lds[T_STEPS & 1];
    float part[4][10];
#pragma unroll
    for (int r = 0; r < 4; r++)
#pragma unroll
        for (int cl = 0; cl < 10; cl++) part[r][cl] = 0.0f;
#pragma unroll
    for (int u = 0; u < 2; u++) {
        const int hcol = 32 * w + 16 * u + l15;
        const int lpbase = 16 * ((hcol >> 3) & 3);
#pragma unroll
        for (int r = 0; r < 4; r++) {
            int m = quad * 4 + r;
            unsigned int hu = Af[(w * 64 + m + lpbase) * 8 + (hcol & 7)];
            union { unsigned int uu; float f; } cv; cv.uu = hu << 16;
            float hh = cv.f;
#pragma unroll
            for (int cl = 0; cl < 10; cl++)
                part[r][cl] += hh * Wph[hcol * 10 + cl];
        }
    }
#pragma unroll
    for (int off = 1; off < 16; off <<= 1)
#pragma unroll
        for (int r = 0; r < 4; r++)
#pragma unroll
            for (int cl = 0; cl < 10; cl++)
                part[r][cl] += __shfl_xor(part[r][cl], off, 64);

    if (tid < MB * 10) outacc[tid] = 0.0f;
    __syncthreads();
    if (l15 == 0) {
#pragma unroll
        for (int r = 0; r < 4; r++) {
            int m = quad * 4 + r;
#pragma unroll
            for (int cl = 0; cl < 10; cl++)
                atomicAdd(&outacc[m * 10 + cl], part[r][cl]);
        }
    }
    __syncthreads();
    if (tid < MB * 10) {
        int m = tid / 10, cl = tid - m * 10;
        out[(blk * MB + m) * 10 + cl] = outacc[tid] + bp[cl];
    }
}

extern "C" void kernel_launch(void* const* d_in, const int* in_sizes, int n_in,
                              void* d_out, int out_size, void* d_ws, size_t ws_size,
                              hipStream_t stream) {
    const int*   x    = (const int*)  d_in[0];
    const float* emb  = (const float*)d_in[1];
    const float* Wgx  = (const float*)d_in[2];
    const float* Wgh  = (const float*)d_in[3];
    const float* bg   = (const float*)d_in[4];
    const float* Wix  = (const float*)d_in[5];
    const float* Wih  = (const float*)d_in[6];
    const float* bi   = (const float*)d_in[7];
    const float* Wfx  = (const float*)d_in[8];
    const float* Wfh  = (const float*)d_in[9];
    const float* bf_  = (const float*)d_in[10];
    const float* Wox  = (const float*)d_in[11];
    const float* Woh  = (const float*)d_in[12];
    const float* bo   = (const float*)d_in[13];
    const float* Wph  = (const float*)d_in[14];
    const float* bp   = (const float*)d_in[15];

    char* ws = (char*)d_ws;
    unsigned short* wswz = (unsigned short*)ws;                   // 576 KB
    unsigned short* sbuf = (unsigned short*)(ws + 9 * 64 * 64 * 16); // 192 KB

    build_wswz<<<NBLK * NKIT, 64, 0, stream>>>(Wgx, Wgh, bg, Wix, Wih, bi,
                                               Wfx, Wfh, bf_, Wox, Woh, bo,
                                               wswz, sbuf);
    lstm_main<<<NBLK, 512, 0, stream>>>(x, emb, Wph, bp, wswz, sbuf,
                                        (float*)d_out);
}

// Round 20
// 1462.319 us; speedup vs baseline: 1.2809x; 1.2809x over previous
//
#include <hip/hip_runtime.h>
#include <stdint.h>

#define T_STEPS 256
#define EMBD 10
#define MB 16          // batch rows per block
#define NBLK 64        // 1024 / MB
#define NKIT 9         // K = 288 = 9 * 32 (256 h + 10 x + 1 bias + pad)

typedef __attribute__((ext_vector_type(8))) short bf16x8;
typedef __attribute__((ext_vector_type(4))) float f32x4;
typedef __attribute__((ext_vector_type(4))) int   i32x4;

__device__ __forceinline__ unsigned short f2bf(float f) {
    union { float f; unsigned int u; } v; v.f = f;
    unsigned int u = v.u;
    unsigned int r = (u + 0x7FFFu + ((u >> 16) & 1u)) >> 16;  // RNE
    return (unsigned short)r;
}
__device__ __forceinline__ float sig_fast(float x) {
    return __frcp_rn(1.0f + exp2f(-1.4426950408889634f * x));
}
__device__ __forceinline__ float tanh_fast(float x) {
    return 1.0f - 2.0f * __frcp_rn(exp2f(2.8853900817779268f * x) + 1.0f);
}

// AGPR park/unpark -- HW-proven (R11/R12/R16/R17/R18 passed; best dur).
// Direct builtin-MFMA consumption of AGPR quads was tried twice (R14, R19)
// and regressed both times: the allocator inserts copies/spills around the
// directly-consumed quads (R19: WRITE_SIZE 3.9->9.4 MB). Keep unpark.
__device__ __forceinline__ i32x4 park_agpr(i32x4 v) {
    i32x4 r;
    asm volatile("v_accvgpr_write_b32 %0, %4\n\t"
                 "v_accvgpr_write_b32 %1, %5\n\t"
                 "v_accvgpr_write_b32 %2, %6\n\t"
                 "v_accvgpr_write_b32 %3, %7"
                 : "=a"(r.x), "=a"(r.y), "=a"(r.z), "=a"(r.w)
                 : "v"(v.x), "v"(v.y), "v"(v.z), "v"(v.w));
    return r;
}
__device__ __forceinline__ i32x4 unpark_agpr(i32x4 a) {
    i32x4 r;
    asm("v_accvgpr_read_b32 %0, %4\n\t"
        "v_accvgpr_read_b32 %1, %5\n\t"
        "v_accvgpr_read_b32 %2, %6\n\t"
        "v_accvgpr_read_b32 %3, %7\n\t"
        "s_nop 1"
        : "=v"(r.x), "=v"(r.y), "=v"(r.z), "=v"(r.w)
        : "a"(a.x), "a"(a.y), "a"(a.z), "a"(a.w));
    return r;
}
__device__ __forceinline__ f32x4 mfma_v(i32x4 a, i32x4 b, f32x4 c) {
    return __builtin_amdgcn_mfma_f32_16x16x32_bf16(
        __builtin_bit_cast(bf16x8, a), __builtin_bit_cast(bf16x8, b), c, 0, 0, 0);
}

// ---------------------------------------------------------------------------
// K1: swizzled bf16 weights Wfull[288][1024] in MFMA B-frag order.
// Main region: [kit 0..8][ntile 0..63][lane] x 16B.
// Stream region (kits 4,7,8): [w][s][gate][u][lane] -- wave-major constant
// offsets (K2 uses s=0 (kit4), s=1 (kit7)).
// ---------------------------------------------------------------------------
__global__ __launch_bounds__(64) void build_wswz(
    const float* __restrict__ Wgx, const float* __restrict__ Wgh, const float* __restrict__ bg,
    const float* __restrict__ Wix, const float* __restrict__ Wih, const float* __restrict__ bi,
    const float* __restrict__ Wfx, const float* __restrict__ Wfh, const float* __restrict__ bf_,
    const float* __restrict__ Wox, const float* __restrict__ Woh, const float* __restrict__ bo,
    unsigned short* __restrict__ wswz, unsigned short* __restrict__ sbuf)
{
    int g   = blockIdx.x / NKIT;   // ntile
    int kit = blockIdx.x % NKIT;
    int lane = threadIdx.x;
    int n = g * 16 + (lane & 15);
    int q = n >> 8;
    int col = n & 255;
    const float* Wh = (q == 0) ? Wgh : (q == 1) ? Wih : (q == 2) ? Wfh : Woh;
    const float* Wx = (q == 0) ? Wgx : (q == 1) ? Wix : (q == 2) ? Wfx : Wox;
    const float* bb = (q == 0) ? bg  : (q == 1) ? bi  : (q == 2) ? bf_ : bo;
    int k0 = kit * 32 + (lane >> 4) * 8;

    int4 out;
    unsigned short* p = (unsigned short*)&out;
#pragma unroll
    for (int jx = 0; jx < 8; jx++) {
        int k = k0 + jx;
        float v = 0.0f;
        if (k < 256)             v = Wh[k * 256 + col];
        else if (k < 256 + EMBD) v = Wx[(k - 256) * 256 + col];
        else if (k == 266)       v = bb[col];
        p[jx] = f2bf(v);
    }
    ((int4*)wswz)[(kit * 64 + g) * 64 + lane] = out;

    if (kit == 4 || kit == 7 || kit == 8) {
        int s    = (kit == 4) ? 0 : (kit == 7) ? 1 : 2;
        int gate = g >> 4;
        int wv   = (g & 15) >> 1;
        int u    = g & 1;
        ((int4*)sbuf)[((((wv * 3 + s) * 4 + gate) * 2 + u) * 64) + lane] = out;
    }
}

// ---------------------------------------------------------------------------
// K2: persistent LSTM. 64 blocks x 512 threads (8 waves, 2 waves/SIMD;
// unified RF = 256/wave: 128 arch + 128 AGPR). R18 structure (best: 1439 us,
// steady 1395) with the per-step x/emb gather spread over ALL 8 waves
// (20 elems/wave) instead of waves 0-3 only -- balances arrival at the
// per-step barrier at zero register cost.
// Wave w owns hcols 32w+16u+l15 (u=0,1) x 4 gates: nt = gate*16 + 2w + u.
// B residency/wave: kits {0,1,2,3} parked AGPR (128 AGPR), kits {5,6} LDS
// (128 KB), kit {8} arch (32 regs), kits {4,7} streamed (128 KB/step/CU)
// via a 4-frag rotating land buffer (consume -> reissue in place).
// Active-CU-normalized counters at R18: VALU ~70% + MFMA ~18% = issue-bound.
// ---------------------------------------------------------------------------
__global__ __launch_bounds__(512)
__attribute__((amdgpu_waves_per_eu(2, 2)))
void lstm_main(
    const int*   __restrict__ xtok,   // [1024][1][256]
    const float* __restrict__ emb,    // [32000][10]
    const float* __restrict__ Wph,    // [256][10]
    const float* __restrict__ bp,     // [10]
    const unsigned short* __restrict__ wswz,
    const unsigned short* __restrict__ sbuf,
    float* __restrict__ out)          // [1024][10]
{
    __shared__ __align__(16) unsigned short A_lds[2][8 * 64 * 8];   // 16 KB (kits 0-7)
    __shared__ __align__(16) unsigned short A8_lds[2][64 * 8];      // 2 KB (kit 8)
    __shared__ __align__(16) i32x4 B_lds[2 * 64 * 64];              // 128 KB (kits 5,6)
    __shared__ float outacc[MB * 10];

    const int tid  = threadIdx.x;
    const int w    = tid >> 6;        // wave 0..7
    const int lane = tid & 63;
    const int quad = lane >> 4;
    const int l15  = lane & 15;
    const int blk  = blockIdx.x;

    // balanced x-gather mapping: idx = w*20 + lane (lanes 0..19), idx<160
    const int gidx   = w * 20 + lane;
    const bool do_g  = (lane < 20) && (gidx < 160);
    const int g_row  = (gidx * 205) >> 11;        // gidx/10 for gidx<160
    const int g_e    = gidx - g_row * 10;

    const i32x4* Bg  = (const i32x4*)wswz;
    const i32x4* SBw = (const i32x4*)sbuf + (size_t)w * (3 * 4 * 2 * 64);

    // --- prologue: LDS B-cache (kits 5,6) ---
    for (int i = tid; i < 2 * 64 * 64; i += 512)
        B_lds[i] = Bg[5 * 4096 + i];

    // --- AGPR-parked B: kits 0..3, [kit][gate][u] = 32 frags = 128 AGPR ---
    i32x4 bag[4][4][2];
#pragma unroll
    for (int s = 0; s < 4; s++)
#pragma unroll
        for (int g = 0; g < 4; g++)
#pragma unroll
            for (int u = 0; u < 2; u++)
                bag[s][g][u] = park_agpr(
                    Bg[(s * 64 + g * 16 + 2 * w + u) * 64 + lane]);

    // --- arch-resident kit 8: [gate][u] = 8 frags = 32 regs ---
    i32x4 b8[4][2];
#pragma unroll
    for (int g = 0; g < 4; g++)
#pragma unroll
        for (int u = 0; u < 2; u++)
            b8[g][u] = Bg[(8 * 64 + g * 16 + 2 * w + u) * 64 + lane];

    // --- rotating land buffer: holds kit4(u=0) on loop entry ---
    i32x4 land[4];
#pragma unroll
    for (int g = 0; g < 4; g++)
        land[g] = SBw[(((0 * 4 + g) * 2 + 0) * 64) + lane];

    // --- init A double buffer: zeros, bias row (both), x_0 (buf 0) ---
    {
        int4 z4 = {0, 0, 0, 0};
        for (int i = tid; i < 1024; i += 512) ((int4*)A_lds)[i] = z4;
        if (tid < 128) ((int4*)A8_lds)[tid] = z4;
    }
    __syncthreads();
    if (tid < 16) {
        // kit8 local k=10 (bias=1.0): lp = m+16, elem 2
        A8_lds[0][(16 + tid) * 8 + 2] = 0x3F80;
        A8_lds[1][(16 + tid) * 8 + 2] = 0x3F80;
    }
    if (do_g) {
        int tok = xtok[(blk * MB + g_row) * T_STEPS + 0];
        float v = emb[tok * EMBD + g_e];
        A8_lds[0][(g_row + 16 * (g_e >> 3)) * 8 + (g_e & 7)] = f2bf(v);
    }
    __syncthreads();

    float c[2][4];
#pragma unroll
    for (int u = 0; u < 2; u++)
#pragma unroll
        for (int r = 0; r < 4; r++) c[u][r] = 0.0f;

    for (int t = 0; t < T_STEPS; t++) {
        const i32x4* Ab  = (const i32x4*)A_lds[t & 1];
        const i32x4* A8b = (const i32x4*)A8_lds[t & 1];
        unsigned short* Aw  = A_lds[(t + 1) & 1];
        unsigned short* A8w = A8_lds[(t + 1) & 1];

        // x(t+1) prefetch (independent; overlaps MFMA; balanced over waves)
        float xval = 0.0f;
        const bool do_x = (t < T_STEPS - 1) && do_g;
        if (do_x) {
            int tok = xtok[(blk * MB + g_row) * T_STEPS + (t + 1)];
            xval = emb[tok * EMBD + g_e];
        }

#pragma unroll
        for (int u = 0; u < 2; u++) {
            const int nu = 1 - u;  // next-pass index (t-invariant addresses)

            f32x4 acc[4];
#pragma unroll
            for (int g = 0; g < 4; g++) acc[g] = (f32x4){0.f, 0.f, 0.f, 0.f};

            // --- kit 4 (streamed; load landed last pass) ---
            {
                i32x4 a4 = Ab[4 * 64 + lane];
#pragma unroll
                for (int g = 0; g < 4; g++) acc[g] = mfma_v(a4, land[g], acc[g]);
            }
            // rotate: issue kit 7(u) into land (consumed ~20 MFMAs later)
#pragma unroll
            for (int g = 0; g < 4; g++)
                land[g] = SBw[(((1 * 4 + g) * 2 + u) * 64) + lane];

            // --- kit 8 (arch-resident) ---
            {
                i32x4 a8 = A8b[lane];
#pragma unroll
                for (int g = 0; g < 4; g++)
                    acc[g] = mfma_v(a8, b8[g][u], acc[g]);
            }
            // --- AGPR kits 0..3 (unpark per use) ---
#pragma unroll
            for (int s = 0; s < 4; s++) {
                i32x4 as_ = Ab[s * 64 + lane];
#pragma unroll
                for (int g = 0; g < 4; g++)
                    acc[g] = mfma_v(as_, unpark_agpr(bag[s][g][u]), acc[g]);
            }
            // --- LDS kit 5 ---
            {
                i32x4 a5 = Ab[5 * 64 + lane];
#pragma unroll
                for (int g = 0; g < 4; g++)
                    acc[g] = mfma_v(a5, B_lds[(g * 16 + 2 * w + u) * 64 + lane], acc[g]);
            }
            // --- kit 7 (streamed; issued this pass, ~20 MFMAs cover) ---
            {
                i32x4 a7 = Ab[7 * 64 + lane];
#pragma unroll
                for (int g = 0; g < 4; g++) acc[g] = mfma_v(a7, land[g], acc[g]);
            }
            // rotate: issue next pass's kit 4 (cross-pass/barrier cover)
#pragma unroll
            for (int g = 0; g < 4; g++)
                land[g] = SBw[(((0 * 4 + g) * 2 + nu) * 64) + lane];

            // --- LDS kit 6 ---
            {
                i32x4 a6 = Ab[6 * 64 + lane];
#pragma unroll
                for (int g = 0; g < 4; g++)
                    acc[g] = mfma_v(a6, B_lds[4096 + (g * 16 + 2 * w + u) * 64 + lane], acc[g]);
            }

            // gate math: z[m][n], m = quad*4+r, n = gate*256 + 32w + 16u + l15
            const int hcol = 32 * w + 16 * u + l15;
            const int lpbase = 16 * ((hcol >> 3) & 3);
#pragma unroll
            for (int r = 0; r < 4; r++) {
                float gg = tanh_fast(acc[0][r]);
                float ii = sig_fast(acc[1][r]);
                float ff = sig_fast(acc[2][r]);
                float oo = sig_fast(acc[3][r]);
                float cn = gg * ii + c[u][r] * ff;
                c[u][r] = cn;
                float hh = tanh_fast(cn) * oo;
                int m = quad * 4 + r;
                Aw[(w * 64 + m + lpbase) * 8 + (hcol & 7)] = f2bf(hh);
            }
        }
        if (t == T_STEPS - 1) break;
        if (do_x)
            A8w[(g_row + 16 * (g_e >> 3)) * 8 + (g_e & 7)] = f2bf(xval);
        __syncthreads();  // single barrier: A(t+1) complete
    }
    __syncthreads();

    // --- epilogue: re-read own h (bf16) from final A buffer, project ---
    const unsigned short* Af = A_lds[T_STEPS & 1];
    float part[4][10];
#pragma unroll
    for (int r = 0; r < 4; r++)
#pragma unroll
        for (int cl = 0; cl < 10; cl++) part[r][cl] = 0.0f;
#pragma unroll
    for (int u = 0; u < 2; u++) {
        const int hcol = 32 * w + 16 * u + l15;
        const int lpbase = 16 * ((hcol >> 3) & 3);
#pragma unroll
        for (int r = 0; r < 4; r++) {
            int m = quad * 4 + r;
            unsigned int hu = Af[(w * 64 + m + lpbase) * 8 + (hcol & 7)];
            union { unsigned int uu; float f; } cv; cv.uu = hu << 16;
            float hh = cv.f;
#pragma unroll
            for (int cl = 0; cl < 10; cl++)
                part[r][cl] += hh * Wph[hcol * 10 + cl];
        }
    }
#pragma unroll
    for (int off = 1; off < 16; off <<= 1)
#pragma unroll
        for (int r = 0; r < 4; r++)
#pragma unroll
            for (int cl = 0; cl < 10; cl++)
                part[r][cl] += __shfl_xor(part[r][cl], off, 64);

    if (tid < MB * 10) outacc[tid] = 0.0f;
    __syncthreads();
    if (l15 == 0) {
#pragma unroll
        for (int r = 0; r < 4; r++) {
            int m = quad * 4 + r;
#pragma unroll
            for (int cl = 0; cl < 10; cl++)
                atomicAdd(&outacc[m * 10 + cl], part[r][cl]);
        }
    }
    __syncthreads();
    if (tid < MB * 10) {
        int m = tid / 10, cl = tid - m * 10;
        out[(blk * MB + m) * 10 + cl] = outacc[tid] + bp[cl];
    }
}

extern "C" void kernel_launch(void* const* d_in, const int* in_sizes, int n_in,
                              void* d_out, int out_size, void* d_ws, size_t ws_size,
                              hipStream_t stream) {
    const int*   x    = (const int*)  d_in[0];
    const float* emb  = (const float*)d_in[1];
    const float* Wgx  = (const float*)d_in[2];
    const float* Wgh  = (const float*)d_in[3];
    const float* bg   = (const float*)d_in[4];
    const float* Wix  = (const float*)d_in[5];
    const float* Wih  = (const float*)d_in[6];
    const float* bi   = (const float*)d_in[7];
    const float* Wfx  = (const float*)d_in[8];
    const float* Wfh  = (const float*)d_in[9];
    const float* bf_  = (const float*)d_in[10];
    const float* Wox  = (const float*)d_in[11];
    const float* Woh  = (const float*)d_in[12];
    const float* bo   = (const float*)d_in[13];
    const float* Wph  = (const float*)d_in[14];
    const float* bp   = (const float*)d_in[15];

    char* ws = (char*)d_ws;
    unsigned short* wswz = (unsigned short*)ws;                   // 576 KB
    unsigned short* sbuf = (unsigned short*)(ws + 9 * 64 * 64 * 16); // 192 KB

    build_wswz<<<NBLK * NKIT, 64, 0, stream>>>(Wgx, Wgh, bg, Wix, Wih, bi,
                                               Wfx, Wfh, bf_, Wox, Woh, bo,
                                               wswz, sbuf);
    lstm_main<<<NBLK, 512, 0, stream>>>(x, emb, Wph, bp, wswz, sbuf,
                                        (float*)d_out);
}

// Round 21
// 1439.941 us; speedup vs baseline: 1.3008x; 1.0155x over previous
//
#include <hip/hip_runtime.h>
#include <stdint.h>

#define T_STEPS 256
#define EMBD 10
#define MB 16          // batch rows per block
#define NBLK 64        // 1024 / MB
#define NKIT 9         // K = 288 = 9 * 32 (256 h + 10 x + 1 bias + pad)

typedef __attribute__((ext_vector_type(8))) short bf16x8;
typedef __attribute__((ext_vector_type(4))) float f32x4;
typedef __attribute__((ext_vector_type(4))) int   i32x4;

__device__ __forceinline__ unsigned short f2bf(float f) {
    union { float f; unsigned int u; } v; v.f = f;
    unsigned int u = v.u;
    unsigned int r = (u + 0x7FFFu + ((u >> 16) & 1u)) >> 16;  // RNE
    return (unsigned short)r;
}
__device__ __forceinline__ float sig_fast(float x) {
    return __frcp_rn(1.0f + exp2f(-1.4426950408889634f * x));
}
__device__ __forceinline__ float tanh_fast(float x) {
    return 1.0f - 2.0f * __frcp_rn(exp2f(2.8853900817779268f * x) + 1.0f);
}

// AGPR park/unpark -- HW-proven (R11/R12/R16/R17/R18). Storage the VGPR
// allocator cannot restream or spill. Direct builtin-MFMA consumption of
// the AGPR quads was tried twice (R14, R19) and regressed both times
// (allocator copies/spills around the directly-consumed quads).
__device__ __forceinline__ i32x4 park_agpr(i32x4 v) {
    i32x4 r;
    asm volatile("v_accvgpr_write_b32 %0, %4\n\t"
                 "v_accvgpr_write_b32 %1, %5\n\t"
                 "v_accvgpr_write_b32 %2, %6\n\t"
                 "v_accvgpr_write_b32 %3, %7"
                 : "=a"(r.x), "=a"(r.y), "=a"(r.z), "=a"(r.w)
                 : "v"(v.x), "v"(v.y), "v"(v.z), "v"(v.w));
    return r;
}
__device__ __forceinline__ i32x4 unpark_agpr(i32x4 a) {
    i32x4 r;
    asm("v_accvgpr_read_b32 %0, %4\n\t"
        "v_accvgpr_read_b32 %1, %5\n\t"
        "v_accvgpr_read_b32 %2, %6\n\t"
        "v_accvgpr_read_b32 %3, %7\n\t"
        "s_nop 1"
        : "=v"(r.x), "=v"(r.y), "=v"(r.z), "=v"(r.w)
        : "a"(a.x), "a"(a.y), "a"(a.z), "a"(a.w));
    return r;
}
__device__ __forceinline__ f32x4 mfma_v(i32x4 a, i32x4 b, f32x4 c) {
    return __builtin_amdgcn_mfma_f32_16x16x32_bf16(
        __builtin_bit_cast(bf16x8, a), __builtin_bit_cast(bf16x8, b), c, 0, 0, 0);
}

// ---------------------------------------------------------------------------
// K1: swizzled bf16 weights Wfull[288][1024] in MFMA B-frag order.
// Main region: [kit 0..8][ntile 0..63][lane] x 16B.
// Stream region (kits 4,7,8): [w][s][gate][u][lane] -- wave-major constant
// offsets (K2 uses s=0 (kit4), s=1 (kit7)).
// ---------------------------------------------------------------------------
__global__ __launch_bounds__(64) void build_wswz(
    const float* __restrict__ Wgx, const float* __restrict__ Wgh, const float* __restrict__ bg,
    const float* __restrict__ Wix, const float* __restrict__ Wih, const float* __restrict__ bi,
    const float* __restrict__ Wfx, const float* __restrict__ Wfh, const float* __restrict__ bf_,
    const float* __restrict__ Wox, const float* __restrict__ Woh, const float* __restrict__ bo,
    unsigned short* __restrict__ wswz, unsigned short* __restrict__ sbuf)
{
    int g   = blockIdx.x / NKIT;   // ntile
    int kit = blockIdx.x % NKIT;
    int lane = threadIdx.x;
    int n = g * 16 + (lane & 15);
    int q = n >> 8;
    int col = n & 255;
    const float* Wh = (q == 0) ? Wgh : (q == 1) ? Wih : (q == 2) ? Wfh : Woh;
    const float* Wx = (q == 0) ? Wgx : (q == 1) ? Wix : (q == 2) ? Wfx : Wox;
    const float* bb = (q == 0) ? bg  : (q == 1) ? bi  : (q == 2) ? bf_ : bo;
    int k0 = kit * 32 + (lane >> 4) * 8;

    int4 out;
    unsigned short* p = (unsigned short*)&out;
#pragma unroll
    for (int jx = 0; jx < 8; jx++) {
        int k = k0 + jx;
        float v = 0.0f;
        if (k < 256)             v = Wh[k * 256 + col];
        else if (k < 256 + EMBD) v = Wx[(k - 256) * 256 + col];
        else if (k == 266)       v = bb[col];
        p[jx] = f2bf(v);
    }
    ((int4*)wswz)[(kit * 64 + g) * 64 + lane] = out;

    if (kit == 4 || kit == 7 || kit == 8) {
        int s    = (kit == 4) ? 0 : (kit == 7) ? 1 : 2;
        int gate = g >> 4;
        int wv   = (g & 15) >> 1;
        int u    = g & 1;
        ((int4*)sbuf)[((((wv * 3 + s) * 4 + gate) * 2 + u) * 64) + lane] = out;
    }
}

// ---------------------------------------------------------------------------
// K2: persistent LSTM -- FINAL (R18 structure, best measured: 1439 us,
// steady ~1395). 64 blocks x 512 threads (8 waves, 2 waves/SIMD; unified
// RF = 256/wave: 128 arch + 128 AGPR).
// Wave w owns hcols 32w+16u+l15 (u=0,1) x 4 gates: nt = gate*16 + 2w + u.
// B residency/wave: kits {0,1,2,3} parked AGPR (128 AGPR), kits {5,6} LDS
// (128 KB), kit {8} arch (32 regs), kits {4,7} streamed (128 KB/step/CU)
// via a 4-frag rotating land buffer: consume kit4 -> reissue kit7
// (in-pass cover) -> consume kit7 -> reissue next-pass kit4 (cross-pass
// cover). K-loop is spill-free (one-time-only WRITE_SIZE). Profile at this
// config: ~88% issue-occupied on active CUs (VALU ~70% + MFMA ~18%) --
// the practical HIP-level floor; further gains need hand-asm scheduling.
// ---------------------------------------------------------------------------
__global__ __launch_bounds__(512)
__attribute__((amdgpu_waves_per_eu(2, 2)))
void lstm_main(
    const int*   __restrict__ xtok,   // [1024][1][256]
    const float* __restrict__ emb,    // [32000][10]
    const float* __restrict__ Wph,    // [256][10]
    const float* __restrict__ bp,     // [10]
    const unsigned short* __restrict__ wswz,
    const unsigned short* __restrict__ sbuf,
    float* __restrict__ out)          // [1024][10]
{
    __shared__ __align__(16) unsigned short A_lds[2][8 * 64 * 8];   // 16 KB (kits 0-7)
    __shared__ __align__(16) unsigned short A8_lds[2][64 * 8];      // 2 KB (kit 8)
    __shared__ __align__(16) i32x4 B_lds[2 * 64 * 64];              // 128 KB (kits 5,6)
    __shared__ float outacc[MB * 10];

    const int tid  = threadIdx.x;
    const int w    = tid >> 6;        // wave 0..7
    const int lane = tid & 63;
    const int quad = lane >> 4;
    const int l15  = lane & 15;
    const int blk  = blockIdx.x;

    const int m_x = tid >> 4;         // x-gather: batch row 0..15 (tid<256)
    const int e_x = tid & 15;         // emb element (valid if <10)

    const i32x4* Bg  = (const i32x4*)wswz;
    const i32x4* SBw = (const i32x4*)sbuf + (size_t)w * (3 * 4 * 2 * 64);

    // --- prologue: LDS B-cache (kits 5,6) ---
    for (int i = tid; i < 2 * 64 * 64; i += 512)
        B_lds[i] = Bg[5 * 4096 + i];

    // --- AGPR-parked B: kits 0..3, [kit][gate][u] = 32 frags = 128 AGPR ---
    i32x4 bag[4][4][2];
#pragma unroll
    for (int s = 0; s < 4; s++)
#pragma unroll
        for (int g = 0; g < 4; g++)
#pragma unroll
            for (int u = 0; u < 2; u++)
                bag[s][g][u] = park_agpr(
                    Bg[(s * 64 + g * 16 + 2 * w + u) * 64 + lane]);

    // --- arch-resident kit 8: [gate][u] = 8 frags = 32 regs ---
    i32x4 b8[4][2];
#pragma unroll
    for (int g = 0; g < 4; g++)
#pragma unroll
        for (int u = 0; u < 2; u++)
            b8[g][u] = Bg[(8 * 64 + g * 16 + 2 * w + u) * 64 + lane];

    // --- rotating land buffer: holds kit4(u=0) on loop entry ---
    i32x4 land[4];
#pragma unroll
    for (int g = 0; g < 4; g++)
        land[g] = SBw[(((0 * 4 + g) * 2 + 0) * 64) + lane];

    // --- init A double buffer: zeros, bias row (both), x_0 (buf 0) ---
    {
        int4 z4 = {0, 0, 0, 0};
        for (int i = tid; i < 1024; i += 512) ((int4*)A_lds)[i] = z4;
        if (tid < 128) ((int4*)A8_lds)[tid] = z4;
    }
    __syncthreads();
    if (tid < 16) {
        // kit8 local k=10 (bias=1.0): lp = m+16, elem 2
        A8_lds[0][(16 + tid) * 8 + 2] = 0x3F80;
        A8_lds[1][(16 + tid) * 8 + 2] = 0x3F80;
    }
    if (tid < 256 && e_x < EMBD) {
        int tok = xtok[(blk * MB + m_x) * T_STEPS + 0];
        float v = emb[tok * EMBD + e_x];
        A8_lds[0][(m_x + 16 * (e_x >> 3)) * 8 + (e_x & 7)] = f2bf(v);
    }
    __syncthreads();

    float c[2][4];
#pragma unroll
    for (int u = 0; u < 2; u++)
#pragma unroll
        for (int r = 0; r < 4; r++) c[u][r] = 0.0f;

    for (int t = 0; t < T_STEPS; t++) {
        const i32x4* Ab  = (const i32x4*)A_lds[t & 1];
        const i32x4* A8b = (const i32x4*)A8_lds[t & 1];
        unsigned short* Aw  = A_lds[(t + 1) & 1];
        unsigned short* A8w = A8_lds[(t + 1) & 1];

        // x(t+1) prefetch (independent; overlaps MFMA)
        float xval = 0.0f;
        const bool do_x = (t < T_STEPS - 1) && (tid < 256) && (e_x < EMBD);
        if ((t < T_STEPS - 1) && (tid < 256)) {
            int tok = xtok[(blk * MB + m_x) * T_STEPS + (t + 1)];
            if (e_x < EMBD) xval = emb[tok * EMBD + e_x];
        }

#pragma unroll
        for (int u = 0; u < 2; u++) {
            const int nu = 1 - u;  // next-pass index (t-invariant addresses)

            f32x4 acc[4];
#pragma unroll
            for (int g = 0; g < 4; g++) acc[g] = (f32x4){0.f, 0.f, 0.f, 0.f};

            // --- kit 4 (streamed; load landed last pass) ---
            {
                i32x4 a4 = Ab[4 * 64 + lane];
#pragma unroll
                for (int g = 0; g < 4; g++) acc[g] = mfma_v(a4, land[g], acc[g]);
            }
            // rotate: issue kit 7(u) into land (consumed ~20 MFMAs later)
#pragma unroll
            for (int g = 0; g < 4; g++)
                land[g] = SBw[(((1 * 4 + g) * 2 + u) * 64) + lane];

            // --- kit 8 (arch-resident) ---
            {
                i32x4 a8 = A8b[lane];
#pragma unroll
                for (int g = 0; g < 4; g++)
                    acc[g] = mfma_v(a8, b8[g][u], acc[g]);
            }
            // --- AGPR kits 0..3 (unpark per use) ---
#pragma unroll
            for (int s = 0; s < 4; s++) {
                i32x4 as_ = Ab[s * 64 + lane];
#pragma unroll
                for (int g = 0; g < 4; g++)
                    acc[g] = mfma_v(as_, unpark_agpr(bag[s][g][u]), acc[g]);
            }
            // --- LDS kit 5 ---
            {
                i32x4 a5 = Ab[5 * 64 + lane];
#pragma unroll
                for (int g = 0; g < 4; g++)
                    acc[g] = mfma_v(a5, B_lds[(g * 16 + 2 * w + u) * 64 + lane], acc[g]);
            }
            // --- kit 7 (streamed; issued this pass, ~20 MFMAs cover) ---
            {
                i32x4 a7 = Ab[7 * 64 + lane];
#pragma unroll
                for (int g = 0; g < 4; g++) acc[g] = mfma_v(a7, land[g], acc[g]);
            }
            // rotate: issue next pass's kit 4 (cross-pass/barrier cover)
#pragma unroll
            for (int g = 0; g < 4; g++)
                land[g] = SBw[(((0 * 4 + g) * 2 + nu) * 64) + lane];

            // --- LDS kit 6 ---
            {
                i32x4 a6 = Ab[6 * 64 + lane];
#pragma unroll
                for (int g = 0; g < 4; g++)
                    acc[g] = mfma_v(a6, B_lds[4096 + (g * 16 + 2 * w + u) * 64 + lane], acc[g]);
            }

            // gate math: z[m][n], m = quad*4+r, n = gate*256 + 32w + 16u + l15
            const int hcol = 32 * w + 16 * u + l15;
            const int lpbase = 16 * ((hcol >> 3) & 3);
#pragma unroll
            for (int r = 0; r < 4; r++) {
                float gg = tanh_fast(acc[0][r]);
                float ii = sig_fast(acc[1][r]);
                float ff = sig_fast(acc[2][r]);
                float oo = sig_fast(acc[3][r]);
                float cn = gg * ii + c[u][r] * ff;
                c[u][r] = cn;
                float hh = tanh_fast(cn) * oo;
                int m = quad * 4 + r;
                Aw[(w * 64 + m + lpbase) * 8 + (hcol & 7)] = f2bf(hh);
            }
        }
        if (t == T_STEPS - 1) break;
        if (do_x)
            A8w[(m_x + 16 * (e_x >> 3)) * 8 + (e_x & 7)] = f2bf(xval);
        __syncthreads();  // single barrier: A(t+1) complete
    }
    __syncthreads();

    // --- epilogue: re-read own h (bf16) from final A buffer, project ---
    const unsigned short* Af = A_lds[T_STEPS & 1];
    float part[4][10];
#pragma unroll
    for (int r = 0; r < 4; r++)
#pragma unroll
        for (int cl = 0; cl < 10; cl++) part[r][cl] = 0.0f;
#pragma unroll
    for (int u = 0; u < 2; u++) {
        const int hcol = 32 * w + 16 * u + l15;
        const int lpbase = 16 * ((hcol >> 3) & 3);
#pragma unroll
        for (int r = 0; r < 4; r++) {
            int m = quad * 4 + r;
            unsigned int hu = Af[(w * 64 + m + lpbase) * 8 + (hcol & 7)];
            union { unsigned int uu; float f; } cv; cv.uu = hu << 16;
            float hh = cv.f;
#pragma unroll
            for (int cl = 0; cl < 10; cl++)
                part[r][cl] += hh * Wph[hcol * 10 + cl];
        }
    }
#pragma unroll
    for (int off = 1; off < 16; off <<= 1)
#pragma unroll
        for (int r = 0; r < 4; r++)
#pragma unroll
            for (int cl = 0; cl < 10; cl++)
                part[r][cl] += __shfl_xor(part[r][cl], off, 64);

    if (tid < MB * 10) outacc[tid] = 0.0f;
    __syncthreads();
    if (l15 == 0) {
#pragma unroll
        for (int r = 0; r < 4; r++) {
            int m = quad * 4 + r;
#pragma unroll
            for (int cl = 0; cl < 10; cl++)
                atomicAdd(&outacc[m * 10 + cl], part[r][cl]);
        }
    }
    __syncthreads();
    if (tid < MB * 10) {
        int m = tid / 10, cl = tid - m * 10;
        out[(blk * MB + m) * 10 + cl] = outacc[tid] + bp[cl];
    }
}

extern "C" void kernel_launch(void* const* d_in, const int* in_sizes, int n_in,
                              void* d_out, int out_size, void* d_ws, size_t ws_size,
                              hipStream_t stream) {
    const int*   x    = (const int*)  d_in[0];
    const float* emb  = (const float*)d_in[1];
    const float* Wgx  = (const float*)d_in[2];
    const float* Wgh  = (const float*)d_in[3];
    const float* bg   = (const float*)d_in[4];
    const float* Wix  = (const float*)d_in[5];
    const float* Wih  = (const float*)d_in[6];
    const float* bi   = (const float*)d_in[7];
    const float* Wfx  = (const float*)d_in[8];
    const float* Wfh  = (const float*)d_in[9];
    const float* bf_  = (const float*)d_in[10];
    const float* Wox  = (const float*)d_in[11];
    const float* Woh  = (const float*)d_in[12];
    const float* bo   = (const float*)d_in[13];
    const float* Wph  = (const float*)d_in[14];
    const float* bp   = (const float*)d_in[15];

    char* ws = (char*)d_ws;
    unsigned short* wswz = (unsigned short*)ws;                   // 576 KB
    unsigned short* sbuf = (unsigned short*)(ws + 9 * 64 * 64 * 16); // 192 KB

    build_wswz<<<NBLK * NKIT, 64, 0, stream>>>(Wgx, Wgh, bg, Wix, Wih, bi,
                                               Wfx, Wfh, bf_, Wox, Woh, bo,
                                               wswz, sbuf);
    lstm_main<<<NBLK, 512, 0, stream>>>(x, emb, Wph, bp, wswz, sbuf,
                                        (float*)d_out);
}